// Round 1
// baseline (432.712 us; speedup 1.0000x reference)
//
#include <hip/hip_runtime.h>
#include <math.h>

// MoE gating: logits = hs @ W^T  (N=32768, D=2560, E=4), softmax, top-2.
// Outputs written as float32 values: [topk_idx (N*2) | topk_weight (N*2) | row_idx (N*2)]

#define N_TOKENS  32768
#define EMBED_DIM 2560
#define N_EXPERTS 4

constexpr int D4            = EMBED_DIM / 4;  // 640 float4 per expert row
constexpr int ROWS_PER_WAVE = 4;
constexpr int BLOCK         = 256;
constexpr int WAVES_PER_BLK = BLOCK / 64;
constexpr int NK            = N_TOKENS * 2;   // elements per output chunk

__global__ __launch_bounds__(BLOCK, 4)
void moe_gate_kernel(const float* __restrict__ hs,
                     const float* __restrict__ w,
                     float* __restrict__ out)
{
    // Weight staged in LDS, original [E][D] row-major layout:
    // lane i reads float4 at d4 = it*64 + lane -> consecutive 16B chunks
    // across the wave -> conflict-free ds_read_b128.
    __shared__ float4 wlds[N_EXPERTS * D4];   // 40 KiB -> 4 blocks/CU

    const float4* __restrict__ w4 = reinterpret_cast<const float4*>(w);
    for (int i = threadIdx.x; i < N_EXPERTS * D4; i += BLOCK)
        wlds[i] = w4[i];
    __syncthreads();

    const int lane = threadIdx.x & 63;
    const int wave = ((int)blockIdx.x * WAVES_PER_BLK) + (threadIdx.x >> 6);
    const int row0 = wave * ROWS_PER_WAVE;
    if (row0 >= N_TOKENS) return;

    const float4* __restrict__ hs4 = reinterpret_cast<const float4*>(hs);

    float acc[ROWS_PER_WAVE][N_EXPERTS];
#pragma unroll
    for (int r = 0; r < ROWS_PER_WAVE; ++r)
#pragma unroll
        for (int e = 0; e < N_EXPERTS; ++e)
            acc[r][e] = 0.0f;

    // Each wave covers 64*4 = 256 floats per iteration; D = 2560 -> 10 iters.
#pragma unroll
    for (int it = 0; it < D4 / 64; ++it) {
        const int d4 = it * 64 + lane;
        float4 wv[N_EXPERTS];
#pragma unroll
        for (int e = 0; e < N_EXPERTS; ++e)
            wv[e] = wlds[e * D4 + d4];

#pragma unroll
        for (int r = 0; r < ROWS_PER_WAVE; ++r) {
            const float4 h = hs4[(size_t)(row0 + r) * D4 + d4];
#pragma unroll
            for (int e = 0; e < N_EXPERTS; ++e) {
                float a = acc[r][e];
                a = fmaf(h.x, wv[e].x, a);
                a = fmaf(h.y, wv[e].y, a);
                a = fmaf(h.z, wv[e].z, a);
                a = fmaf(h.w, wv[e].w, a);
                acc[r][e] = a;
            }
        }
    }

    // Butterfly reduce each of the 16 partials across the 64 lanes.
#pragma unroll
    for (int r = 0; r < ROWS_PER_WAVE; ++r)
#pragma unroll
        for (int e = 0; e < N_EXPERTS; ++e) {
            float v = acc[r][e];
#pragma unroll
            for (int m = 1; m < 64; m <<= 1)
                v += __shfl_xor(v, m, 64);
            acc[r][e] = v;
        }

    // Lanes 0..3 each finalize one row (all lanes hold full sums).
    if (lane < ROWS_PER_WAVE) {
        const int row = row0 + lane;
        float l[N_EXPERTS];
#pragma unroll
        for (int e = 0; e < N_EXPERTS; ++e) l[e] = acc[lane][e];

        const float m  = fmaxf(fmaxf(l[0], l[1]), fmaxf(l[2], l[3]));
        float p[N_EXPERTS];
        float s = 0.0f;
#pragma unroll
        for (int e = 0; e < N_EXPERTS; ++e) { p[e] = expf(l[e] - m); s += p[e]; }
        const float inv = 1.0f / s;
#pragma unroll
        for (int e = 0; e < N_EXPERTS; ++e) p[e] *= inv;

        // top-2 with ties -> lower index (strict > scan), matching lax.top_k
        int i0 = 0; float b0 = p[0];
#pragma unroll
        for (int e = 1; e < N_EXPERTS; ++e)
            if (p[e] > b0) { b0 = p[e]; i0 = e; }
        int i1 = -1; float b1 = -1.0f;
#pragma unroll
        for (int e = 0; e < N_EXPERTS; ++e)
            if (e != i0 && p[e] > b1) { b1 = p[e]; i1 = e; }

        // outputs (all as float32 values)
        out[(size_t)row * 2 + 0]          = (float)i0;
        out[(size_t)row * 2 + 1]          = (float)i1;
        out[NK + (size_t)row * 2 + 0]     = b0;
        out[NK + (size_t)row * 2 + 1]     = b1;
        out[2 * NK + (size_t)row * 2 + 0] = (float)row;              // j=0: 0*N + i
        out[2 * NK + (size_t)row * 2 + 1] = (float)(N_TOKENS + row); // j=1: N + i
    }
}

extern "C" void kernel_launch(void* const* d_in, const int* in_sizes, int n_in,
                              void* d_out, int out_size, void* d_ws, size_t ws_size,
                              hipStream_t stream) {
    const float* hs = (const float*)d_in[0];
    const float* w  = (const float*)d_in[1];
    float* out      = (float*)d_out;

    const int total_waves = N_TOKENS / ROWS_PER_WAVE;   // 8192
    const int grid        = total_waves / WAVES_PER_BLK; // 2048
    moe_gate_kernel<<<grid, BLOCK, 0, stream>>>(hs, w, out);
}